// Round 3
// baseline (51.571 us; speedup 1.0000x reference)
//
#include <hip/hip_runtime.h>

// out[b,s,d] = x[b,s,d] + pe[s,d]
//   d < 512 : pe = sin(s * 10000^(-2d/1024))
//   d >= 512: pe = cos(s * 10000^(-(2*(d-512)+1)/1024))
// B=8, S=4096, D=1024, fp32.
// Memory-bound. x (128 MiB) fits in the 256 MiB Infinity Cache; the output
// is write-once, never re-read. Nontemporal stores keep the write stream
// from evicting x -> reads come from L3 on timed replays, HBM traffic ~=
// writes only (134 MB -> ~21us floor at 6.3 TB/s).
// Native clang vector type: __builtin_nontemporal_store rejects
// HIP_vector_type (R2 compile fail) but accepts ext_vector_type.

typedef float floatx4 __attribute__((ext_vector_type(4)));

__global__ __launch_bounds__(256) void pe_add_kernel(const floatx4* __restrict__ x,
                                                     floatx4* __restrict__ out) {
    constexpr int S = 4096;
    constexpr int B = 8;
    constexpr int ROW4 = 1024 / 4;        // float4s per row = 256

    const int s = blockIdx.x;             // 0..4095
    const int t = threadIdx.x;            // 0..255
    const int d0 = t * 4;

    const float pos = (float)s;
    const float NLOG2_10000_OVER_D = -13.287712379549449f * (1.0f / 1024.0f);

    // 512 % 4 == 0 -> all 4 lanes of this thread are on the same side.
    float pe[4];
    if (d0 < 512) {
        #pragma unroll
        for (int j = 0; j < 4; ++j) {
            const float k = 2.0f * (float)(d0 + j);
            const float invfreq = exp2f(k * NLOG2_10000_OVER_D);
            pe[j] = sinf(pos * invfreq);
        }
    } else {
        #pragma unroll
        for (int j = 0; j < 4; ++j) {
            const float k = 2.0f * (float)(d0 - 512 + j) + 1.0f;
            const float invfreq = exp2f(k * NLOG2_10000_OVER_D);
            pe[j] = cosf(pos * invfreq);
        }
    }

    const int rowbase = s * ROW4 + t;
    #pragma unroll
    for (int b = 0; b < B; ++b) {
        const int idx = b * (S * ROW4) + rowbase;
        floatx4 v = x[idx];
        v.x += pe[0];
        v.y += pe[1];
        v.z += pe[2];
        v.w += pe[3];
        __builtin_nontemporal_store(v, &out[idx]);
    }
}

extern "C" void kernel_launch(void* const* d_in, const int* in_sizes, int n_in,
                              void* d_out, int out_size, void* d_ws, size_t ws_size,
                              hipStream_t stream) {
    const floatx4* x = (const floatx4*)d_in[0];
    floatx4* out = (floatx4*)d_out;
    // grid: one block per s-row
    pe_add_kernel<<<dim3(4096), dim3(256), 0, stream>>>(x, out);
}

// Round 4
// 46.513 us; speedup vs baseline: 1.1087x; 1.1087x over previous
//
#include <hip/hip_runtime.h>

// out[b,s,d] = x[b,s,d] + pe[s,d]
//   d < 512 : pe = sin(s * 10000^(-2d/1024))
//   d >= 512: pe = cos(s * 10000^(-(2*(d-512)+1)/1024))
// B=8, S=4096, D=1024, fp32.
// Memory-bound: 268 MB compulsory traffic -> ~43us at 6.3 TB/s.
// R3 lesson: nontemporal store had zero effect on FETCH (MALL is memory-side;
// CU hints don't reach it) -> reverted. FETCH=64MiB is steady-state L3
// capacity (x+out = 256 MiB = L3 size), not fixable from the kernel.
// R4 change: explicit MLP — issue all 8 batch loads before any add/store.
// VGPR 28 -> ~64, giving each wave 8 loads in flight instead of ~1.

typedef float floatx4 __attribute__((ext_vector_type(4)));

__global__ __launch_bounds__(256) void pe_add_kernel(const floatx4* __restrict__ x,
                                                     floatx4* __restrict__ out) {
    constexpr int S = 4096;
    constexpr int B = 8;
    constexpr int ROW4 = 1024 / 4;        // float4s per row = 256

    const int s = blockIdx.x;             // 0..4095
    const int t = threadIdx.x;            // 0..255
    const int d0 = t * 4;

    const int rowbase = s * ROW4 + t;

    // Issue ALL batch loads first — 8 global_load_dwordx4 in flight per lane.
    floatx4 v[B];
    #pragma unroll
    for (int b = 0; b < B; ++b) {
        v[b] = x[b * (S * ROW4) + rowbase];
    }

    // pe computed once per thread while loads are in flight.
    const float pos = (float)s;
    const float NLOG2_10000_OVER_D = -13.287712379549449f * (1.0f / 1024.0f);

    // 512 % 4 == 0 -> all 4 lanes of this thread are on the same side.
    float pe[4];
    if (d0 < 512) {
        #pragma unroll
        for (int j = 0; j < 4; ++j) {
            const float k = 2.0f * (float)(d0 + j);
            const float invfreq = exp2f(k * NLOG2_10000_OVER_D);
            pe[j] = sinf(pos * invfreq);
        }
    } else {
        #pragma unroll
        for (int j = 0; j < 4; ++j) {
            const float k = 2.0f * (float)(d0 - 512 + j) + 1.0f;
            const float invfreq = exp2f(k * NLOG2_10000_OVER_D);
            pe[j] = cosf(pos * invfreq);
        }
    }

    #pragma unroll
    for (int b = 0; b < B; ++b) {
        floatx4 r = v[b];
        r.x += pe[0];
        r.y += pe[1];
        r.z += pe[2];
        r.w += pe[3];
        out[b * (S * ROW4) + rowbase] = r;
    }
}

extern "C" void kernel_launch(void* const* d_in, const int* in_sizes, int n_in,
                              void* d_out, int out_size, void* d_ws, size_t ws_size,
                              hipStream_t stream) {
    const floatx4* x = (const floatx4*)d_in[0];
    floatx4* out = (floatx4*)d_out;
    // grid: one block per s-row
    pe_add_kernel<<<dim3(4096), dim3(256), 0, stream>>>(x, out);
}